// Round 2
// baseline (280.867 us; speedup 1.0000x reference)
//
#include <hip/hip_runtime.h>

#define NEG_W 8.0f
#define EPS 1e-7f
#define TPB 256
#define BLOCKS 2048              // 8 blocks/CU x 256 CU -> fully resident, zero churn
#define STRIDE (BLOCKS * TPB)    // 524288 threads; vec4-index stride between slots
#define SUBT 8                   // sub-tiles per thread, 2 vec4 each -> 16 vec4/thread
// total vec4 = SUBT * 2 * STRIDE = 8,388,608 = N/4 exactly

typedef float f32x4 __attribute__((ext_vector_type(4)));
typedef int   i32x4 __attribute__((ext_vector_type(4)));

// Round 4 theory: round-1 falsified "serialized loads" (pinning all 8 loads
// live changed SGPR count but NOT duration; an L3-resident replay pass ran at
// the same 97us as an HBM pass -> cap is CU-side, not HBM). New theory: the
// one-burst-per-block shape gives bursty MLP -- loads drain to zero during
// compute/reduce/block-churn, so time-averaged in-flight bytes (Little's law)
// cap delivered BW at ~2.6 TB/s vs 6.3 TB/s for a continuous grid-stride
// stream. Fix: persistent blocks + register double-buffer so loads are in
// flight continuously, like the 6.29 TB/s copy ubench.
__global__ __launch_bounds__(TPB) void bce_partial(
    const f32x4* __restrict__ out4, const i32x4* __restrict__ tgt4,
    float* __restrict__ partials) {
  const int tid = blockIdx.x * TPB + threadIdx.x;

  float acc0 = 0.0f, acc1 = 0.0f, acc2 = 0.0f, acc3 = 0.0f;

#define BCE_BODY(o, t)                                              \
  {                                                                 \
    float x0 = (t.x == 1) ? (o.x + EPS) : (1.0f - o.x + EPS);       \
    float w0 = (t.x == 1) ? 1.0f : NEG_W;                           \
    float x1 = (t.y == 1) ? (o.y + EPS) : (1.0f - o.y + EPS);       \
    float w1 = (t.y == 1) ? 1.0f : NEG_W;                           \
    float x2 = (t.z == 1) ? (o.z + EPS) : (1.0f - o.z + EPS);       \
    float w2 = (t.z == 1) ? 1.0f : NEG_W;                           \
    float x3 = (t.w == 1) ? (o.w + EPS) : (1.0f - o.w + EPS);       \
    float w3 = (t.w == 1) ? 1.0f : NEG_W;                           \
    acc0 = fmaf(w0, __logf(x0), acc0);                              \
    acc1 = fmaf(w1, __logf(x1), acc1);                              \
    acc2 = fmaf(w2, __logf(x2), acc2);                              \
    acc3 = fmaf(w3, __logf(x3), acc3);                              \
  }

  // Prologue: load sub-tile 0 into A-buffer.
  int p = tid;
  f32x4 oa0 = out4[p], oa1 = out4[p + STRIDE];
  i32x4 ta0 = tgt4[p], ta1 = tgt4[p + STRIDE];

  // 2-deep software pipeline, unroll-by-2 so the double-buffer rotation is
  // pure register renaming (no movs). unroll 1 on the outer loop keeps the
  // compiler from hoisting all 32 loads into one giant burst (VGPR blowup).
#pragma unroll 1
  for (int s = 0; s < SUBT; s += 2) {
    const int pb = p + 2 * STRIDE;   // sub-tile s+1 (always in range: s+1 <= 7)
    f32x4 ob0 = out4[pb], ob1 = out4[pb + STRIDE];
    i32x4 tb0 = tgt4[pb], tb1 = tgt4[pb + STRIDE];

    BCE_BODY(oa0, ta0)
    BCE_BODY(oa1, ta1)

    const int pa = p + 4 * STRIDE;   // sub-tile s+2
    if (s + 2 < SUBT) {              // wave-uniform branch
      oa0 = out4[pa];  oa1 = out4[pa + STRIDE];
      ta0 = tgt4[pa];  ta1 = tgt4[pa + STRIDE];
    }

    BCE_BODY(ob0, tb0)
    BCE_BODY(ob1, tb1)
    p = pa;
  }
#undef BCE_BODY

  float sum = -((acc0 + acc1) + (acc2 + acc3));

  // wave64 butterfly reduce
  for (int off = 32; off > 0; off >>= 1)
    sum += __shfl_down(sum, off, 64);

  __shared__ float wsum[TPB / 64];
  const int lane = threadIdx.x & 63;
  const int wid = threadIdx.x >> 6;
  if (lane == 0) wsum[wid] = sum;
  __syncthreads();
  if (threadIdx.x == 0) {
    float s = 0.0f;
    for (int w = 0; w < TPB / 64; ++w) s += wsum[w];
    partials[blockIdx.x] = s;
  }
}

// Kernel 2: single block reduces BLOCKS float partials in double, writes mean.
__global__ __launch_bounds__(TPB) void bce_finalize(
    const float* __restrict__ partials, float* __restrict__ out, int nblocks,
    double inv_n) {
  double s = 0.0;
  for (int i = threadIdx.x; i < nblocks; i += TPB) s += (double)partials[i];
  for (int off = 32; off > 0; off >>= 1)
    s += __shfl_down(s, off, 64);
  __shared__ double wsum[TPB / 64];
  const int lane = threadIdx.x & 63;
  const int wid = threadIdx.x >> 6;
  if (lane == 0) wsum[wid] = s;
  __syncthreads();
  if (threadIdx.x == 0) {
    double tot = 0.0;
    for (int w = 0; w < TPB / 64; ++w) tot += wsum[w];
    out[0] = (float)(tot * inv_n);
  }
}

extern "C" void kernel_launch(void* const* d_in, const int* in_sizes, int n_in,
                              void* d_out, int out_size, void* d_ws, size_t ws_size,
                              hipStream_t stream) {
  const f32x4* out4 = (const f32x4*)d_in[0];
  const i32x4* tgt4 = (const i32x4*)d_in[1];
  const int n = in_sizes[0];          // 33554432 = SUBT*2*STRIDE*4 exactly
  float* partials = (float*)d_ws;     // 2048 * 4 B = 8 KB scratch
  (void)n;

  bce_partial<<<BLOCKS, TPB, 0, stream>>>(out4, tgt4, partials);
  bce_finalize<<<1, TPB, 0, stream>>>(partials, (float*)d_out, BLOCKS,
                                      1.0 / (double)33554432);
}

// Round 4
// 252.934 us; speedup vs baseline: 1.1104x; 1.1104x over previous
//
#include <hip/hip_runtime.h>

#define NEG_W 8.0f
#define EPS 1e-7f
#define TPB 256
#define VPT 4                 // 4 float4 + 4 int4 per thread, fully unrolled
#define BLOCKS 8192           // 8192*256*4 float4 = 8,388,608 = N/4 exactly

typedef float f32x4 __attribute__((ext_vector_type(4)));
typedef int   i32x4 __attribute__((ext_vector_type(4)));

// Round 6 (= round-5 resubmit; r5 died to a container-infra failure, kernel
// never ran). History: r1 pinned all 8 loads live (null), r2 persistent grid
// + reg double-buffer (regression 103us) -> MLP/schedule theories falsified;
// cap is upstream of CUs. L3-resident replay pass runs at the SAME 97us as an
// HBM pass -> backing-store-agnostic. Theory: per-DIRECTION fabric ceiling
// ~3.15 TB/s (m13 copy 6.29 = 3.15r + 3.15w; no measured kernel exceeds ~3.15
// one-way). We read 2.7 TB/s = 86% of that. Discriminator: nt loads bypass L3.
//   fabric theory  -> FETCH_SIZE ~doubles (~260 GB-KB), dur ~92-97us (null)
//   L3-path theory -> dur drops to 60-75us
__global__ __launch_bounds__(TPB) void bce_partial(
    const f32x4* __restrict__ out4, const i32x4* __restrict__ tgt4,
    float* __restrict__ partials) {
  const int base = blockIdx.x * (TPB * VPT) + threadIdx.x;

  f32x4 o[VPT];
  i32x4 t[VPT];
#pragma unroll
  for (int u = 0; u < VPT; ++u) {
    const int idx = base + u * TPB;   // coalesced within each unroll slot
    o[u] = __builtin_nontemporal_load(out4 + idx);
    t[u] = __builtin_nontemporal_load(tgt4 + idx);
  }
  __builtin_amdgcn_sched_barrier(0);  // keep the 8-load burst clustered

  float acc0 = 0.0f, acc1 = 0.0f, acc2 = 0.0f, acc3 = 0.0f;
#pragma unroll
  for (int u = 0; u < VPT; ++u) {
    float x0 = (t[u].x == 1) ? (o[u].x + EPS) : (1.0f - o[u].x + EPS);
    float w0 = (t[u].x == 1) ? 1.0f : NEG_W;
    float x1 = (t[u].y == 1) ? (o[u].y + EPS) : (1.0f - o[u].y + EPS);
    float w1 = (t[u].y == 1) ? 1.0f : NEG_W;
    float x2 = (t[u].z == 1) ? (o[u].z + EPS) : (1.0f - o[u].z + EPS);
    float w2 = (t[u].z == 1) ? 1.0f : NEG_W;
    float x3 = (t[u].w == 1) ? (o[u].w + EPS) : (1.0f - o[u].w + EPS);
    float w3 = (t[u].w == 1) ? 1.0f : NEG_W;
    acc0 = fmaf(w0, __logf(x0), acc0);
    acc1 = fmaf(w1, __logf(x1), acc1);
    acc2 = fmaf(w2, __logf(x2), acc2);
    acc3 = fmaf(w3, __logf(x3), acc3);
  }
  float sum = -((acc0 + acc1) + (acc2 + acc3));

  // wave64 butterfly reduce
  for (int off = 32; off > 0; off >>= 1)
    sum += __shfl_down(sum, off, 64);

  __shared__ float wsum[TPB / 64];
  const int lane = threadIdx.x & 63;
  const int wid = threadIdx.x >> 6;
  if (lane == 0) wsum[wid] = sum;
  __syncthreads();
  if (threadIdx.x == 0) {
    float s = 0.0f;
    for (int w = 0; w < TPB / 64; ++w) s += wsum[w];
    partials[blockIdx.x] = s;
  }
}

// Kernel 2: single block reduces BLOCKS float partials in double, writes mean.
__global__ __launch_bounds__(TPB) void bce_finalize(
    const float* __restrict__ partials, float* __restrict__ out, int nblocks,
    double inv_n) {
  double s = 0.0;
  for (int i = threadIdx.x; i < nblocks; i += TPB) s += (double)partials[i];
  for (int off = 32; off > 0; off >>= 1)
    s += __shfl_down(s, off, 64);
  __shared__ double wsum[TPB / 64];
  const int lane = threadIdx.x & 63;
  const int wid = threadIdx.x >> 6;
  if (lane == 0) wsum[wid] = s;
  __syncthreads();
  if (threadIdx.x == 0) {
    double tot = 0.0;
    for (int w = 0; w < TPB / 64; ++w) tot += wsum[w];
    out[0] = (float)(tot * inv_n);
  }
}

extern "C" void kernel_launch(void* const* d_in, const int* in_sizes, int n_in,
                              void* d_out, int out_size, void* d_ws, size_t ws_size,
                              hipStream_t stream) {
  const f32x4* out4 = (const f32x4*)d_in[0];
  const i32x4* tgt4 = (const i32x4*)d_in[1];
  const int n = in_sizes[0];          // 33554432 = BLOCKS*TPB*VPT*4 exactly
  float* partials = (float*)d_ws;     // 8192 * 4 B = 32 KB scratch
  (void)n;

  bce_partial<<<BLOCKS, TPB, 0, stream>>>(out4, tgt4, partials);
  bce_finalize<<<1, TPB, 0, stream>>>(partials, (float*)d_out, BLOCKS,
                                      1.0 / (double)33554432);
}

// Round 5
// 248.747 us; speedup vs baseline: 1.1291x; 1.0168x over previous
//
#include <hip/hip_runtime.h>

#define NEG_W 8.0f
#define EPS 1e-7f
#define TPB 256
#define VPT 8                 // 8 float4 + 8 int4 per thread, one deep burst
#define BLOCKS 4096           // 4096*256*8 float4 = 8,388,608 = N/4 exactly

typedef float f32x4 __attribute__((ext_vector_type(4)));
typedef int   i32x4 __attribute__((ext_vector_type(4)));

// Round 7. r6 (nt loads, L3 bypass) WIN: bce_partial 97 -> ~73us (headline
// 273.8 -> 252.9); L3-hit-path contention confirmed as the old cap. Harness
// fillBufferAligned dispatches prove ~6.9 TB/s single-direction (write) is
// sustainable -> the 3.15 TB/s per-direction theory is dead; read path has
// headroom. New regime: nt reads take full HBM latency (~900cy vs ~200cy
// L2/L3) -> Little's law needs ~2x more bytes in flight. This round: VPT
// 4 -> 8 (256 B/lane per burst, 16 loads back-to-back), BLOCKS 8192 -> 4096.
// Predict bce_partial ~55-62us, headline ~235-240; null => read-path ceiling
// at ~3.7 TB/s, declare roofline.
__global__ __launch_bounds__(TPB) void bce_partial(
    const f32x4* __restrict__ out4, const i32x4* __restrict__ tgt4,
    float* __restrict__ partials) {
  const int base = blockIdx.x * (TPB * VPT) + threadIdx.x;

  f32x4 o[VPT];
  i32x4 t[VPT];
#pragma unroll
  for (int u = 0; u < VPT; ++u) {
    const int idx = base + u * TPB;   // coalesced within each unroll slot
    o[u] = __builtin_nontemporal_load(out4 + idx);
    t[u] = __builtin_nontemporal_load(tgt4 + idx);
  }
  __builtin_amdgcn_sched_barrier(0);  // keep the 16-load burst clustered

  float acc0 = 0.0f, acc1 = 0.0f, acc2 = 0.0f, acc3 = 0.0f;
#pragma unroll
  for (int u = 0; u < VPT; ++u) {
    float x0 = (t[u].x == 1) ? (o[u].x + EPS) : (1.0f - o[u].x + EPS);
    float w0 = (t[u].x == 1) ? 1.0f : NEG_W;
    float x1 = (t[u].y == 1) ? (o[u].y + EPS) : (1.0f - o[u].y + EPS);
    float w1 = (t[u].y == 1) ? 1.0f : NEG_W;
    float x2 = (t[u].z == 1) ? (o[u].z + EPS) : (1.0f - o[u].z + EPS);
    float w2 = (t[u].z == 1) ? 1.0f : NEG_W;
    float x3 = (t[u].w == 1) ? (o[u].w + EPS) : (1.0f - o[u].w + EPS);
    float w3 = (t[u].w == 1) ? 1.0f : NEG_W;
    acc0 = fmaf(w0, __logf(x0), acc0);
    acc1 = fmaf(w1, __logf(x1), acc1);
    acc2 = fmaf(w2, __logf(x2), acc2);
    acc3 = fmaf(w3, __logf(x3), acc3);
  }
  float sum = -((acc0 + acc1) + (acc2 + acc3));

  // wave64 butterfly reduce
  for (int off = 32; off > 0; off >>= 1)
    sum += __shfl_down(sum, off, 64);

  __shared__ float wsum[TPB / 64];
  const int lane = threadIdx.x & 63;
  const int wid = threadIdx.x >> 6;
  if (lane == 0) wsum[wid] = sum;
  __syncthreads();
  if (threadIdx.x == 0) {
    float s = 0.0f;
    for (int w = 0; w < TPB / 64; ++w) s += wsum[w];
    partials[blockIdx.x] = s;
  }
}

// Kernel 2: single block reduces BLOCKS float partials in double, writes mean.
__global__ __launch_bounds__(TPB) void bce_finalize(
    const float* __restrict__ partials, float* __restrict__ out, int nblocks,
    double inv_n) {
  double s = 0.0;
  for (int i = threadIdx.x; i < nblocks; i += TPB) s += (double)partials[i];
  for (int off = 32; off > 0; off >>= 1)
    s += __shfl_down(s, off, 64);
  __shared__ double wsum[TPB / 64];
  const int lane = threadIdx.x & 63;
  const int wid = threadIdx.x >> 6;
  if (lane == 0) wsum[wid] = s;
  __syncthreads();
  if (threadIdx.x == 0) {
    double tot = 0.0;
    for (int w = 0; w < TPB / 64; ++w) tot += wsum[w];
    out[0] = (float)(tot * inv_n);
  }
}

extern "C" void kernel_launch(void* const* d_in, const int* in_sizes, int n_in,
                              void* d_out, int out_size, void* d_ws, size_t ws_size,
                              hipStream_t stream) {
  const f32x4* out4 = (const f32x4*)d_in[0];
  const i32x4* tgt4 = (const i32x4*)d_in[1];
  const int n = in_sizes[0];          // 33554432 = BLOCKS*TPB*VPT*4 exactly
  float* partials = (float*)d_ws;     // 4096 * 4 B = 16 KB scratch
  (void)n;

  bce_partial<<<BLOCKS, TPB, 0, stream>>>(out4, tgt4, partials);
  bce_finalize<<<1, TPB, 0, stream>>>(partials, (float*)d_out, BLOCKS,
                                      1.0 / (double)33554432);
}